// Round 2
// baseline (211.610 us; speedup 1.0000x reference)
//
#include <hip/hip_runtime.h>

// GlobalFusion: scatter global rows into a dense 3D grid hash, then per local
// point gather the coarse-scale global feature row and concat with local row.
//
// scale ratio = (4,4,4) -> floor-div by 4 == arithmetic >>2
// C = 64 floats per feature row; output row = 128 floats = 32 float4.
//
// R2: 32 threads/row -> one perfectly contiguous 1KB store per wave;
//     nontemporal hints on the streaming traffic (lf read, out write) to keep
//     grid + global_features L2/L3-resident.

#define SCALE_SHIFT 2
#define C4 16            // 64 floats = 16 float4 per input row
#define OUT4 32          // 128 floats = 32 float4 per output row

typedef float f32x4 __attribute__((ext_vector_type(4)));

__global__ void build_grid_kernel(const int* __restrict__ gcoords,
                                  int n_global,
                                  const int* __restrict__ gs_ptr,
                                  int* __restrict__ grid) {
    int i = blockIdx.x * blockDim.x + threadIdx.x;
    if (i >= n_global) return;
    int gs = *gs_ptr;
    int x = gcoords[3 * i + 0];
    int y = gcoords[3 * i + 1];
    int z = gcoords[3 * i + 2];
    // reference: grid.at[flat].max(row_index) -> atomicMax resolves duplicates
    atomicMax(&grid[(x * gs + y) * gs + z], i);
}

__global__ void __launch_bounds__(256)
fuse_kernel(const f32x4* __restrict__ lf4,   // n_local  x 16
            const f32x4* __restrict__ gf4,   // n_global x 16
            const int* __restrict__ lcoords, // n_local x 3
            const int* __restrict__ lbase,   // 3
            const int* __restrict__ gbase,   // 3
            const int* __restrict__ grid,    // gs^3
            int n_local,
            const int* __restrict__ gs_ptr,
            f32x4* __restrict__ out4)        // n_local x 32
{
    int t = blockIdx.x * blockDim.x + threadIdx.x;
    int row = t >> 5;          // 32 threads per row
    int j   = t & 31;
    if (row >= n_local) return;

    f32x4 v;
    if (j < 16) {
        // local half: streaming read, no reuse -> nontemporal
        v = __builtin_nontemporal_load(&lf4[(size_t)row * C4 + j]);
    } else {
        int gs = *gs_ptr;
        int gx = ((lcoords[3 * row + 0] + lbase[0]) >> SCALE_SHIFT) - gbase[0];
        int gy = ((lcoords[3 * row + 1] + lbase[1]) >> SCALE_SHIFT) - gbase[1];
        int gz = ((lcoords[3 * row + 2] + lbase[2]) >> SCALE_SHIFT) - gbase[2];
        bool inb = ((unsigned)gx < (unsigned)gs) &
                   ((unsigned)gy < (unsigned)gs) &
                   ((unsigned)gz < (unsigned)gs);
        int cx = min(max(gx, 0), gs - 1);
        int cy = min(max(gy, 0), gs - 1);
        int cz = min(max(gz, 0), gs - 1);
        int idx = grid[(cx * gs + cy) * gs + cz];  // cached: grid is reused
        v = (f32x4)(0.f, 0.f, 0.f, 0.f);
        if (inb && idx >= 0) {
            v = gf4[(size_t)idx * C4 + (j - 16)]; // cached: gf reused across rows
        }
    }
    // one fully-contiguous 1KB store per wave, streaming -> nontemporal
    __builtin_nontemporal_store(v, &out4[(size_t)t]);
}

extern "C" void kernel_launch(void* const* d_in, const int* in_sizes, int n_in,
                              void* d_out, int out_size, void* d_ws, size_t ws_size,
                              hipStream_t stream) {
    const float* lf = (const float*)d_in[0];
    const float* gf = (const float*)d_in[1];
    const int*   lc = (const int*)d_in[2];
    const int*   gc = (const int*)d_in[3];
    const int*   lb = (const int*)d_in[4];
    const int*   gb = (const int*)d_in[5];
    // d_in[6] = local_spatial_size (unused), d_in[7] = global_spatial_size
    const int*   gs_ptr = (const int*)d_in[7];

    int n_local  = in_sizes[0] / 64;
    int n_global = in_sizes[1] / 64;

    // grid hash lives in workspace: 128^3 int32 = 8 MiB, init to -1 (0xFF)
    int* grid = (int*)d_ws;
    const size_t grid_bytes = (size_t)128 * 128 * 128 * sizeof(int);
    hipMemsetAsync(d_ws, 0xFF, grid_bytes, stream);

    build_grid_kernel<<<(n_global + 255) / 256, 256, 0, stream>>>(
        gc, n_global, gs_ptr, grid);

    long long threads = (long long)n_local * 32;
    int blocks = (int)((threads + 255) / 256);
    fuse_kernel<<<blocks, 256, 0, stream>>>(
        (const f32x4*)lf, (const f32x4*)gf, lc, lb, gb, grid,
        n_local, gs_ptr, (f32x4*)d_out);
}

// Round 3
// 148.799 us; speedup vs baseline: 1.4221x; 1.4221x over previous
//
#include <hip/hip_runtime.h>

// GlobalFusion: scatter global rows into a dense 3D grid hash, then per local
// point gather the coarse-scale global feature row and concat with local row.
//
// scale ratio = (4,4,4) -> floor-div by 4 == arithmetic >>2
// C = 64 floats per feature row; output row = 128 floats = 32 float4.
//
// R3: R1 structure (16 threads/row, non-divergent, both halves per thread),
//     single change: nontemporal hints on streaming lf-load + out-stores.

#define SCALE_SHIFT 2
#define C4 16            // 64 floats = 16 float4 per input row
#define OUT4 32          // 128 floats = 32 float4 per output row

typedef float f32x4 __attribute__((ext_vector_type(4)));

__global__ void build_grid_kernel(const int* __restrict__ gcoords,
                                  int n_global,
                                  const int* __restrict__ gs_ptr,
                                  int* __restrict__ grid) {
    int i = blockIdx.x * blockDim.x + threadIdx.x;
    if (i >= n_global) return;
    int gs = *gs_ptr;
    int x = gcoords[3 * i + 0];
    int y = gcoords[3 * i + 1];
    int z = gcoords[3 * i + 2];
    // reference: grid.at[flat].max(row_index) -> atomicMax resolves duplicates
    atomicMax(&grid[(x * gs + y) * gs + z], i);
}

__global__ void __launch_bounds__(256)
fuse_kernel(const f32x4* __restrict__ lf4,   // n_local  x 16
            const f32x4* __restrict__ gf4,   // n_global x 16
            const int* __restrict__ lcoords, // n_local x 3
            const int* __restrict__ lbase,   // 3
            const int* __restrict__ gbase,   // 3
            const int* __restrict__ grid,    // gs^3
            int n_local,
            const int* __restrict__ gs_ptr,
            f32x4* __restrict__ out4)        // n_local x 32
{
    int t = blockIdx.x * blockDim.x + threadIdx.x;
    int row = t >> 4;          // 16 threads per row
    int j   = t & 15;
    if (row >= n_local) return;
    int gs = *gs_ptr;

    // local half: streaming copy (coalesced float4, single-use -> nt)
    f32x4 lv = __builtin_nontemporal_load(&lf4[(size_t)row * C4 + j]);
    __builtin_nontemporal_store(lv, &out4[(size_t)row * OUT4 + j]);

    // gathered half (grid + gf reads stay cached)
    int gx = ((lcoords[3 * row + 0] + lbase[0]) >> SCALE_SHIFT) - gbase[0];
    int gy = ((lcoords[3 * row + 1] + lbase[1]) >> SCALE_SHIFT) - gbase[1];
    int gz = ((lcoords[3 * row + 2] + lbase[2]) >> SCALE_SHIFT) - gbase[2];
    bool inb = ((unsigned)gx < (unsigned)gs) &
               ((unsigned)gy < (unsigned)gs) &
               ((unsigned)gz < (unsigned)gs);
    int cx = min(max(gx, 0), gs - 1);
    int cy = min(max(gy, 0), gs - 1);
    int cz = min(max(gz, 0), gs - 1);
    int idx = grid[(cx * gs + cy) * gs + cz];

    f32x4 v = (f32x4)(0.f, 0.f, 0.f, 0.f);
    if (inb && idx >= 0) {
        v = gf4[(size_t)idx * C4 + j];
    }
    __builtin_nontemporal_store(v, &out4[(size_t)row * OUT4 + C4 + j]);
}

extern "C" void kernel_launch(void* const* d_in, const int* in_sizes, int n_in,
                              void* d_out, int out_size, void* d_ws, size_t ws_size,
                              hipStream_t stream) {
    const float* lf = (const float*)d_in[0];
    const float* gf = (const float*)d_in[1];
    const int*   lc = (const int*)d_in[2];
    const int*   gc = (const int*)d_in[3];
    const int*   lb = (const int*)d_in[4];
    const int*   gb = (const int*)d_in[5];
    // d_in[6] = local_spatial_size (unused), d_in[7] = global_spatial_size
    const int*   gs_ptr = (const int*)d_in[7];

    int n_local  = in_sizes[0] / 64;
    int n_global = in_sizes[1] / 64;

    // grid hash lives in workspace: 128^3 int32 = 8 MiB, init to -1 (0xFF)
    int* grid = (int*)d_ws;
    const size_t grid_bytes = (size_t)128 * 128 * 128 * sizeof(int);
    hipMemsetAsync(d_ws, 0xFF, grid_bytes, stream);

    build_grid_kernel<<<(n_global + 255) / 256, 256, 0, stream>>>(
        gc, n_global, gs_ptr, grid);

    long long threads = (long long)n_local * 16;
    int blocks = (int)((threads + 255) / 256);
    fuse_kernel<<<blocks, 256, 0, stream>>>(
        (const f32x4*)lf, (const f32x4*)gf, lc, lb, gb, grid,
        n_local, gs_ptr, (f32x4*)d_out);
}